// Round 14
// baseline (581.883 us; speedup 1.0000x reference)
//
#include <hip/hip_runtime.h>
#include <hip/hip_bf16.h>
#include <stdint.h>

#define TOKENS 4096
#define DDIM 1024
#define FDIM 4096
#define NEXP 8
#define BM 256
#define BN 128
#define BK2 32

typedef __attribute__((ext_vector_type(4))) float f32x4;
typedef __attribute__((ext_vector_type(8))) short short8;

__device__ __forceinline__ unsigned short f2bf(float f) {
    union { float f; uint32_t u; } v; v.f = f;
    uint32_t u = v.u;
    return (unsigned short)((u + 0x7fff + ((u >> 16) & 1)) >> 16);
}

#define BARRIER() asm volatile("s_barrier" ::: "memory")
#define WAIT_VM0() asm volatile("s_waitcnt vmcnt(0)" ::: "memory")
#define WAIT_LGKM0() asm volatile("s_waitcnt lgkmcnt(0)" ::: "memory")
#define GLDS(SRC, DST) __builtin_amdgcn_global_load_lds( \
    (const __attribute__((address_space(1))) void*)(SRC), \
    (__attribute__((address_space(3))) void*)(DST), 16, 0, 0)

// opaque asm LDS read: explicit waits control all ordering (rule #18 applied at use)
__device__ __forceinline__ short8 dsr(uint32_t addr) {
    short8 d;
    asm volatile("ds_read_b128 %0, %1" : "=v"(d) : "v"(addr));
    return d;
}

// ---------------- X f32 -> bf16 ----------------
__global__ __launch_bounds__(256) void cvt_x(const float* __restrict__ x,
                                             unsigned short* __restrict__ xb, int n) {
    int i = (blockIdx.x * 256 + threadIdx.x) * 8;
    if (i >= n) return;
    float4 a = *(const float4*)(x + i);
    float4 b = *(const float4*)(x + i + 4);
    short8 o;
    o[0] = f2bf(a.x); o[1] = f2bf(a.y); o[2] = f2bf(a.z); o[3] = f2bf(a.w);
    o[4] = f2bf(b.x); o[5] = f2bf(b.y); o[6] = f2bf(b.z); o[7] = f2bf(b.w);
    *(short8*)(xb + i) = o;
}

// ------------- transpose + cvt: in [E][R][C] f32 -> out [E][C][R] bf16 -------------
__global__ __launch_bounds__(256) void transpose_cvt(const float* __restrict__ in,
                                                     unsigned short* __restrict__ out,
                                                     int R, int C) {
    __shared__ float tile[32][33];
    int e = blockIdx.z;
    int r0 = blockIdx.y * 32, c0 = blockIdx.x * 32;
    const float* src = in + (size_t)e * R * C;
    unsigned short* dst = out + (size_t)e * R * C;
    int t = threadIdx.x;
    int rr = t >> 3;
    int cc = (t & 7) * 4;
    float4 v = *(const float4*)(src + (size_t)(r0 + rr) * C + c0 + cc);
    tile[rr][cc + 0] = v.x; tile[rr][cc + 1] = v.y;
    tile[rr][cc + 2] = v.z; tile[rr][cc + 3] = v.w;
    __syncthreads();
    int oc = rr;
    int orr = cc;
    ushort4 o;
    o.x = f2bf(tile[orr + 0][oc]);
    o.y = f2bf(tile[orr + 1][oc]);
    o.z = f2bf(tile[orr + 2][oc]);
    o.w = f2bf(tile[orr + 3][oc]);
    *(ushort4*)(dst + (size_t)(c0 + oc) * R + r0 + orr) = o;
}

// ---------------- router: top-2 of 8 logits, build expert lists ----------------
__global__ __launch_bounds__(256) void router(const float* __restrict__ x,
                                              const float* __restrict__ wr,
                                              int* __restrict__ cnt,
                                              int* __restrict__ list) {
    __shared__ float wl[NEXP * DDIM];
    int t = threadIdx.x;
    for (int i = t; i < NEXP * DDIM; i += 256) wl[i] = wr[i];
    __syncthreads();
    int tok = blockIdx.x * 4 + (t >> 6);
    int lane = t & 63;
    float acc[NEXP];
#pragma unroll
    for (int e = 0; e < NEXP; e++) acc[e] = 0.f;
    const float* xr = x + (size_t)tok * DDIM;
    for (int d = lane; d < DDIM; d += 64) {
        float xv = xr[d];
#pragma unroll
        for (int e = 0; e < NEXP; e++) acc[e] += xv * wl[e * DDIM + d];
    }
#pragma unroll
    for (int e = 0; e < NEXP; e++) {
#pragma unroll
        for (int off = 32; off; off >>= 1) acc[e] += __shfl_xor(acc[e], off);
    }
    if (lane == 0) {
        int e1 = 0; float v1 = acc[0];
        for (int e = 1; e < NEXP; e++) if (acc[e] > v1) { v1 = acc[e]; e1 = e; }
        int e2 = -1; float v2 = -1e30f;
        for (int e = 0; e < NEXP; e++) if (e != e1 && acc[e] > v2) { v2 = acc[e]; e2 = e; }
        int p1 = atomicAdd(&cnt[e1], 1);
        list[e1 * TOKENS + p1] = tok;
        int p2 = atomicAdd(&cnt[e2], 1);
        list[e2 * TOKENS + p2] = tok;
    }
}

// ---------------- setup: offsets, work bases (BM=256), queue reset ----------------
__global__ void setup(const int* __restrict__ cnt, int* __restrict__ off,
                      int* __restrict__ wbA, int* __restrict__ wbB,
                      int* __restrict__ qctr) {
    if (threadIdx.x == 0) {
        int s = 0, ta = 0, tb = 0;
        for (int e = 0; e < NEXP; e++) {
            off[e] = s; s += cnt[e];
            wbA[e] = ta; wbB[e] = tb;
            int ntm = (cnt[e] + BM - 1) >> 8;
            ta += ntm * (FDIM / BN);        // pass A: 32 n-tiles of 128
            tb += ntm * (DDIM / BN) * 4;    // pass B: 8 n-tiles x 4 k-chunks
        }
        wbA[NEXP] = ta; wbB[NEXP] = tb;
        qctr[0] = 0; qctr[1] = 0;
    }
}

// ---- persistent grouped GEMM: BM=256 x BN=128, BK=32, 2-slot ring, 512 thr, 3 blk/CU ----
// R3-proven drain order: stage(next, FIRST) -> asm ds_read -> lgkm0 -> sched_barrier -> MFMA
// -> vmcnt(0) -> s_barrier. 48 KB LDS -> 3 blocks/CU; bounds (512,2) = R11-proven no-spill.
template <bool GATHER_A, bool SILU, int KSPLIT>
__global__ __launch_bounds__(512, 2) void gemm_moe14(
    const unsigned short* __restrict__ Abase,
    const unsigned short* __restrict__ Wt,      // [E][NW][KD] bf16
    const int* __restrict__ cnt, const int* __restrict__ off,
    const int* __restrict__ list,
    const int* __restrict__ wbase,
    int* __restrict__ qctr,
    unsigned short* __restrict__ Hout,          // SILU out, stride NW
    float* __restrict__ Yout,                   // atomic out, stride NW
    int KD, int KLEN, int NW) {
    __shared__ alignas(16) unsigned short As[2][BM * BK2];  // 2 x 16 KB
    __shared__ alignas(16) unsigned short Bs[2][BN * BK2];  // 2 x 8 KB
    __shared__ int wsh;

    const int t = threadIdx.x;
    const int lane = t & 63;
    const int wid = t >> 6;
    const int wm = wid >> 1, wn = wid & 1;     // 4M x 2N waves
    const int r16 = lane & 15, g = lane >> 4;
    const int total = wbase[NEXP];

    // frag addresses within slot 0; chunk g stored at g^((row>>1)&3) (both-sides swizzle)
    const uint32_t asB = (uint32_t)(uintptr_t)&As[0][0];
    const uint32_t bsB = (uint32_t)(uintptr_t)&Bs[0][0];
    uint32_t aAdr[4], bAdr[4];
#pragma unroll
    for (int mi = 0; mi < 4; mi++) {
        int row = wm * 64 + mi * 16 + r16;                 // 0..255
        aAdr[mi] = asB + row * 64 + ((g ^ ((row >> 1) & 3)) << 4);
    }
#pragma unroll
    for (int nj = 0; nj < 4; nj++) {
        int row = wn * 64 + nj * 16 + r16;                 // 0..127
        bAdr[nj] = bsB + row * 64 + ((g ^ ((row >> 1) & 3)) << 4);
    }

    for (;;) {
        if (t == 0) wsh = atomicAdd(qctr, 1);
        __syncthreads();
        int w = wsh;
        if (w >= total) break;

        // ---- decode: expert e; (n-tile [, k-chunk]) outer, m-tile inner ----
        int e = 0;
        while (e < NEXP - 1 && w >= wbase[e + 1]) e++;
        w -= wbase[e];
        const int n_e = cnt[e];
        const int ntm = (n_e + BM - 1) >> 8;
        int combined = w / ntm;
        const int mtile = w - combined * ntm;
        const int kc = (KSPLIT > 1) ? (combined & (KSPLIT - 1)) : 0;
        const int idx = (KSPLIT > 1) ? (combined / KSPLIT) : combined;
        const int m0 = mtile * BM;
        const int n0 = idx * BN;
        const int base = off[e];
        const int k0 = kc * KLEN;

        // ---- staging pointers: A 2 chunks/thread; B 1 chunk/thread (16 B each) ----
        const unsigned short* pA[2];
        int ldsA[2];
#pragma unroll
        for (int i = 0; i < 2; i++) {
            int c = i * 512 + t;                 // 0..1023
            int row = c >> 2, p = c & 3;         // row 0..255
            int cg = p ^ ((row >> 1) & 3);
            int arow = m0 + row; if (arow >= n_e) arow = n_e - 1;
            size_t grow = GATHER_A ? (size_t)list[e * TOKENS + arow] : (size_t)(base + arow);
            pA[i] = Abase + grow * (size_t)KD + k0 + (cg << 3);
            ldsA[i] = c * 16;
        }
        const unsigned short* pB;
        int ldsB;
        {
            int c = t;                           // 0..511
            int row = c >> 2, p = c & 3;         // row 0..127
            int cg = p ^ ((row >> 1) & 3);
            pB = Wt + ((size_t)e * NW + n0 + row) * (size_t)KD + k0 + (cg << 3);
            ldsB = c * 16;
        }

        f32x4 acc[4][4];
#pragma unroll
        for (int i = 0; i < 4; i++)
#pragma unroll
            for (int j = 0; j < 4; j++) acc[i][j] = f32x4{0.f, 0.f, 0.f, 0.f};

        // ---- prologue: stage tile 0 into slot 0 (3 GLDS/thread) ----
#pragma unroll
        for (int i = 0; i < 2; i++) { GLDS(pA[i], (char*)As[0] + ldsA[i]); pA[i] += BK2; }
        GLDS(pB, (char*)Bs[0] + ldsB); pB += BK2;
        WAIT_VM0();
        BARRIER();

        const int NT = KLEN / BK2;
        for (int tk = 0; tk < NT; ++tk) {
            const int cur = tk & 1;
            const uint32_t oA = cur ? 16384u : 0u;
            const uint32_t oB = cur ? 8192u : 0u;

            // stage next tile FIRST: loads fly over this iteration's ds_read+MFMA
            if (tk + 1 < NT) {
                char* Ad = (char*)As[cur ^ 1];
                char* Bd = (char*)Bs[cur ^ 1];
#pragma unroll
                for (int i = 0; i < 2; i++) { GLDS(pA[i], Ad + ldsA[i]); pA[i] += BK2; }
                GLDS(pB, Bd + ldsB); pB += BK2;
            }

            // fragment loads: opaque asm ds_read_b128 from compute slot
            short8 a0 = dsr(aAdr[0] + oA);
            short8 a1 = dsr(aAdr[1] + oA);
            short8 a2 = dsr(aAdr[2] + oA);
            short8 a3 = dsr(aAdr[3] + oA);
            short8 b0 = dsr(bAdr[0] + oB);
            short8 b1 = dsr(bAdr[1] + oB);
            short8 b2 = dsr(bAdr[2] + oB);
            short8 b3 = dsr(bAdr[3] + oB);
            WAIT_LGKM0();
            __builtin_amdgcn_sched_barrier(0);   // rule #18

            __builtin_amdgcn_s_setprio(1);
            acc[0][0] = __builtin_amdgcn_mfma_f32_16x16x32_bf16(a0, b0, acc[0][0], 0, 0, 0);
            acc[0][1] = __builtin_amdgcn_mfma_f32_16x16x32_bf16(a0, b1, acc[0][1], 0, 0, 0);
            acc[0][2] = __builtin_amdgcn_mfma_f32_16x16x32_bf16(a0, b2, acc[0][2], 0, 0, 0);
            acc[0][3] = __builtin_amdgcn_mfma_f32_16x16x32_bf16(a0, b3, acc[0][3], 0, 0, 0);
            acc[1][0] = __builtin_amdgcn_mfma_f32_16x16x32_bf16(a1, b0, acc[1][0], 0, 0, 0);
            acc[1][1] = __builtin_amdgcn_mfma_f32_16x16x32_bf16(a1, b1, acc[1][1], 0, 0, 0);
            acc[1][2] = __builtin_amdgcn_mfma_f32_16x16x32_bf16(a1, b2, acc[1][2], 0, 0, 0);
            acc[1][3] = __builtin_amdgcn_mfma_f32_16x16x32_bf16(a1, b3, acc[1][3], 0, 0, 0);
            acc[2][0] = __builtin_amdgcn_mfma_f32_16x16x32_bf16(a2, b0, acc[2][0], 0, 0, 0);
            acc[2][1] = __builtin_amdgcn_mfma_f32_16x16x32_bf16(a2, b1, acc[2][1], 0, 0, 0);
            acc[2][2] = __builtin_amdgcn_mfma_f32_16x16x32_bf16(a2, b2, acc[2][2], 0, 0, 0);
            acc[2][3] = __builtin_amdgcn_mfma_f32_16x16x32_bf16(a2, b3, acc[2][3], 0, 0, 0);
            acc[3][0] = __builtin_amdgcn_mfma_f32_16x16x32_bf16(a3, b0, acc[3][0], 0, 0, 0);
            acc[3][1] = __builtin_amdgcn_mfma_f32_16x16x32_bf16(a3, b1, acc[3][1], 0, 0, 0);
            acc[3][2] = __builtin_amdgcn_mfma_f32_16x16x32_bf16(a3, b2, acc[3][2], 0, 0, 0);
            acc[3][3] = __builtin_amdgcn_mfma_f32_16x16x32_bf16(a3, b3, acc[3][3], 0, 0, 0);
            __builtin_amdgcn_s_setprio(0);

            // next tile fully resident before anyone reads it (2 sibling blocks cover)
            if (tk + 1 < NT) {
                WAIT_VM0();
                BARRIER();
            }
        }

        // ---- epilogue: row = m0+wm*64+mi*16+g*4+q; col = n0+wn*64+nj*16+r16 ----
#pragma unroll
        for (int mi = 0; mi < 4; ++mi) {
#pragma unroll
            for (int nj = 0; nj < 4; ++nj) {
#pragma unroll
                for (int qq = 0; qq < 4; ++qq) {
                    int lr = wm * 64 + mi * 16 + g * 4 + qq;
                    if (m0 + lr < n_e) {
                        int col = n0 + wn * 64 + nj * 16 + r16;
                        float v = acc[mi][nj][qq];
                        if (SILU) {
                            v = v / (1.f + __expf(-v));
                            Hout[(size_t)(base + m0 + lr) * NW + col] = f2bf(v);
                        } else {
                            int tok = list[e * TOKENS + m0 + lr];
                            atomicAdd(&Yout[(size_t)tok * NW + col], v);
                        }
                    }
                }
            }
        }
    }
}

extern "C" void kernel_launch(void* const* d_in, const int* in_sizes, int n_in,
                              void* d_out, int out_size, void* d_ws, size_t ws_size,
                              hipStream_t stream) {
    const float* X  = (const float*)d_in[0];
    const float* Wr = (const float*)d_in[1];
    const float* W1 = (const float*)d_in[2];
    const float* W2 = (const float*)d_in[3];
    float* Y = (float*)d_out;

    char* ws = (char*)d_ws;
    int* cnt  = (int*)(ws + 0);
    int* off  = (int*)(ws + 64);
    int* wbA  = (int*)(ws + 128);
    int* wbB  = (int*)(ws + 192);
    int* qctr = (int*)(ws + 256);
    int* list = (int*)(ws + 1024);                               // 128 KB
    unsigned short* Xb = (unsigned short*)(ws + (1ull << 20));   // 8 MB
    unsigned short* WT = (unsigned short*)(ws + (16ull << 20));  // 64 MB (W1T, then W2T)
    unsigned short* H  = (unsigned short*)(ws + (80ull << 20));  // 64 MB

    hipMemsetAsync(d_out, 0, (size_t)out_size * sizeof(float), stream);
    hipMemsetAsync(cnt, 0, 32, stream);

    cvt_x<<<TOKENS * DDIM / (256 * 8), 256, 0, stream>>>(X, Xb, TOKENS * DDIM);
    router<<<TOKENS / 4, 256, 0, stream>>>(X, Wr, cnt, list);
    setup<<<1, 64, 0, stream>>>(cnt, off, wbA, wbB, qctr);

    // W1 [E][D][F] -> W1T [E][F][D] bf16
    transpose_cvt<<<dim3(FDIM / 32, DDIM / 32, NEXP), 256, 0, stream>>>(W1, WT, DDIM, FDIM);
    // Pass A: H[slot][F] = silu(X[tok] @ W1[e]); K=1024, 32 n-tiles of 128
    gemm_moe14<true, true, 1><<<768, 512, 0, stream>>>(
        Xb, WT, cnt, off, list, wbA, qctr + 0, H, nullptr, DDIM, DDIM, FDIM);

    // W2 [E][F][D] -> W2T [E][D][F] bf16 (reuses WT)
    transpose_cvt<<<dim3(DDIM / 32, FDIM / 32, NEXP), 256, 0, stream>>>(W2, WT, FDIM, DDIM);
    // Pass B: Y[tok][D] += H[slot] @ W2[e]; 8 n-tiles x 4 k-chunks of 1024
    gemm_moe14<false, false, 4><<<768, 512, 0, stream>>>(
        H, WT, cnt, off, list, wbB, qctr + 1, nullptr, Y, FDIM, FDIM / 4, DDIM);
}

// Round 15
// 564.071 us; speedup vs baseline: 1.0316x; 1.0316x over previous
//
#include <hip/hip_runtime.h>
#include <hip/hip_bf16.h>
#include <stdint.h>

#define TOKENS 4096
#define DDIM 1024
#define FDIM 4096
#define NEXP 8
#define BM 256
#define BN 256
#define BK2 32

typedef __attribute__((ext_vector_type(4))) float f32x4;
typedef __attribute__((ext_vector_type(8))) short short8;

__device__ __forceinline__ unsigned short f2bf(float f) {
    union { float f; uint32_t u; } v; v.f = f;
    uint32_t u = v.u;
    return (unsigned short)((u + 0x7fff + ((u >> 16) & 1)) >> 16);
}

#define BARRIER() asm volatile("s_barrier" ::: "memory")
#define WAIT_VM0() asm volatile("s_waitcnt vmcnt(0)" ::: "memory")
#define WAIT_VM4() asm volatile("s_waitcnt vmcnt(4)" ::: "memory")
#define WAIT_LGKM0() asm volatile("s_waitcnt lgkmcnt(0)" ::: "memory")
#define GLDS(SRC, DST) __builtin_amdgcn_global_load_lds( \
    (const __attribute__((address_space(1))) void*)(SRC), \
    (__attribute__((address_space(3))) void*)(DST), 16, 0, 0)

// opaque asm LDS read: explicit waits control all ordering (rule #18 applied at use)
__device__ __forceinline__ short8 dsr(uint32_t addr) {
    short8 d;
    asm volatile("ds_read_b128 %0, %1" : "=v"(d) : "v"(addr));
    return d;
}

// ---------------- X f32 -> bf16 ----------------
__global__ __launch_bounds__(256) void cvt_x(const float* __restrict__ x,
                                             unsigned short* __restrict__ xb, int n) {
    int i = (blockIdx.x * 256 + threadIdx.x) * 8;
    if (i >= n) return;
    float4 a = *(const float4*)(x + i);
    float4 b = *(const float4*)(x + i + 4);
    short8 o;
    o[0] = f2bf(a.x); o[1] = f2bf(a.y); o[2] = f2bf(a.z); o[3] = f2bf(a.w);
    o[4] = f2bf(b.x); o[5] = f2bf(b.y); o[6] = f2bf(b.z); o[7] = f2bf(b.w);
    *(short8*)(xb + i) = o;
}

// ------------- transpose + cvt: in [E][R][C] f32 -> out [E][C][R] bf16 -------------
__global__ __launch_bounds__(256) void transpose_cvt(const float* __restrict__ in,
                                                     unsigned short* __restrict__ out,
                                                     int R, int C) {
    __shared__ float tile[32][33];
    int e = blockIdx.z;
    int r0 = blockIdx.y * 32, c0 = blockIdx.x * 32;
    const float* src = in + (size_t)e * R * C;
    unsigned short* dst = out + (size_t)e * R * C;
    int t = threadIdx.x;
    int rr = t >> 3;
    int cc = (t & 7) * 4;
    float4 v = *(const float4*)(src + (size_t)(r0 + rr) * C + c0 + cc);
    tile[rr][cc + 0] = v.x; tile[rr][cc + 1] = v.y;
    tile[rr][cc + 2] = v.z; tile[rr][cc + 3] = v.w;
    __syncthreads();
    int oc = rr;
    int orr = cc;
    ushort4 o;
    o.x = f2bf(tile[orr + 0][oc]);
    o.y = f2bf(tile[orr + 1][oc]);
    o.z = f2bf(tile[orr + 2][oc]);
    o.w = f2bf(tile[orr + 3][oc]);
    *(ushort4*)(dst + (size_t)(c0 + oc) * R + r0 + orr) = o;
}

// ---------------- router: top-2 of 8 logits, build expert lists ----------------
__global__ __launch_bounds__(256) void router(const float* __restrict__ x,
                                              const float* __restrict__ wr,
                                              int* __restrict__ cnt,
                                              int* __restrict__ list) {
    __shared__ float wl[NEXP * DDIM];
    int t = threadIdx.x;
    for (int i = t; i < NEXP * DDIM; i += 256) wl[i] = wr[i];
    __syncthreads();
    int tok = blockIdx.x * 4 + (t >> 6);
    int lane = t & 63;
    float acc[NEXP];
#pragma unroll
    for (int e = 0; e < NEXP; e++) acc[e] = 0.f;
    const float* xr = x + (size_t)tok * DDIM;
    for (int d = lane; d < DDIM; d += 64) {
        float xv = xr[d];
#pragma unroll
        for (int e = 0; e < NEXP; e++) acc[e] += xv * wl[e * DDIM + d];
    }
#pragma unroll
    for (int e = 0; e < NEXP; e++) {
#pragma unroll
        for (int off = 32; off; off >>= 1) acc[e] += __shfl_xor(acc[e], off);
    }
    if (lane == 0) {
        int e1 = 0; float v1 = acc[0];
        for (int e = 1; e < NEXP; e++) if (acc[e] > v1) { v1 = acc[e]; e1 = e; }
        int e2 = -1; float v2 = -1e30f;
        for (int e = 0; e < NEXP; e++) if (e != e1 && acc[e] > v2) { v2 = acc[e]; e2 = e; }
        int p1 = atomicAdd(&cnt[e1], 1);
        list[e1 * TOKENS + p1] = tok;
        int p2 = atomicAdd(&cnt[e2], 1);
        list[e2 * TOKENS + p2] = tok;
    }
}

// ---------------- setup: offsets, work bases (BM=256 tiles), queue reset ----------------
__global__ void setup(const int* __restrict__ cnt, int* __restrict__ off,
                      int* __restrict__ wbA, int* __restrict__ wbB,
                      int* __restrict__ qctr) {
    if (threadIdx.x == 0) {
        int s = 0, ta = 0, tb = 0;
        for (int e = 0; e < NEXP; e++) {
            off[e] = s; s += cnt[e];
            wbA[e] = ta; wbB[e] = tb;
            int ntm = (cnt[e] + BM - 1) >> 8;
            ta += ntm * (FDIM / BN);        // pass A: 16 n-tiles of 256
            tb += ntm * (DDIM / BN) * 4;    // pass B: 4 n-tiles x 4 k-chunks
        }
        wbA[NEXP] = ta; wbB[NEXP] = tb;
        qctr[0] = 0; qctr[1] = 0;
    }
}

// ---- persistent grouped GEMM: BM=BN=256, BK=32, 3-slot ring, 512 thr, 1 blk/CU ----
// R8 skeleton verbatim (counted vmcnt, prefetch distance 2), AI=128 FLOP/staged-byte.
// 8 waves 2M x 4N; per-wave output 128x64; MFMA in 2 sub-steps to bound reg liveness.
template <bool GATHER_A, bool SILU, int KSPLIT>
__global__ __launch_bounds__(512, 2) void gemm_moe15(
    const unsigned short* __restrict__ Abase,
    const unsigned short* __restrict__ Wt,      // [E][NW][KD] bf16
    const int* __restrict__ cnt, const int* __restrict__ off,
    const int* __restrict__ list,
    const int* __restrict__ wbase,
    int* __restrict__ qctr,
    unsigned short* __restrict__ Hout,          // SILU out, stride NW
    float* __restrict__ Yout,                   // atomic out, stride NW
    int KD, int KLEN, int NW) {
    __shared__ alignas(16) unsigned short As[3][BM * BK2];  // 3 x 16 KB
    __shared__ alignas(16) unsigned short Bs[3][BN * BK2];  // 3 x 16 KB
    __shared__ int wsh;

    const int t = threadIdx.x;
    const int lane = t & 63;
    const int wid = t >> 6;
    const int wm = wid >> 2, wn = wid & 3;     // 2M x 4N waves
    const int r16 = lane & 15, g = lane >> 4;
    const int total = wbase[NEXP];

    // frag addresses within slot 0; chunk g stored at g^((row>>1)&3) (both-sides swizzle)
    const uint32_t asB = (uint32_t)(uintptr_t)&As[0][0];
    const uint32_t bsB = (uint32_t)(uintptr_t)&Bs[0][0];
    uint32_t aAdr[8], bAdr[4];
#pragma unroll
    for (int mi = 0; mi < 8; mi++) {
        int row = wm * 128 + mi * 16 + r16;                // 0..255
        aAdr[mi] = asB + row * 64 + ((g ^ ((row >> 1) & 3)) << 4);
    }
#pragma unroll
    for (int nj = 0; nj < 4; nj++) {
        int row = wn * 64 + nj * 16 + r16;                 // 0..255
        bAdr[nj] = bsB + row * 64 + ((g ^ ((row >> 1) & 3)) << 4);
    }

    for (;;) {
        if (t == 0) wsh = atomicAdd(qctr, 1);
        __syncthreads();
        int w = wsh;
        if (w >= total) break;

        // ---- decode: expert e; (n-tile [, k-chunk]) outer, m-tile inner ----
        int e = 0;
        while (e < NEXP - 1 && w >= wbase[e + 1]) e++;
        w -= wbase[e];
        const int n_e = cnt[e];
        const int ntm = (n_e + BM - 1) >> 8;
        int combined = w / ntm;
        const int mtile = w - combined * ntm;
        const int kc = (KSPLIT > 1) ? (combined & (KSPLIT - 1)) : 0;
        const int idx = (KSPLIT > 1) ? (combined / KSPLIT) : combined;
        const int m0 = mtile * BM;
        const int n0 = idx * BN;
        const int base = off[e];
        const int k0 = kc * KLEN;

        // ---- staging pointers: 2 A + 2 B chunks of 16 B per thread per tile ----
        const unsigned short* pA[2];
        const unsigned short* pB[2];
        int ldsOff[2];
#pragma unroll
        for (int i = 0; i < 2; i++) {
            int c = i * 512 + t;                 // 0..1023
            int row = c >> 2, p = c & 3;         // row 0..255
            int cg = p ^ ((row >> 1) & 3);
            int arow = m0 + row; if (arow >= n_e) arow = n_e - 1;
            size_t grow = GATHER_A ? (size_t)list[e * TOKENS + arow] : (size_t)(base + arow);
            pA[i] = Abase + grow * (size_t)KD + k0 + (cg << 3);
            pB[i] = Wt + ((size_t)e * NW + n0 + row) * (size_t)KD + k0 + (cg << 3);
            ldsOff[i] = c * 16;
        }

        f32x4 acc[8][4];
#pragma unroll
        for (int i = 0; i < 8; i++)
#pragma unroll
            for (int j = 0; j < 4; j++) acc[i][j] = f32x4{0.f, 0.f, 0.f, 0.f};

        // ---- prologue: stage tiles 0,1 into slots 0,1 (8 GLDS/thread) ----
#pragma unroll
        for (int s = 0; s < 2; ++s) {
#pragma unroll
            for (int i = 0; i < 2; i++) { GLDS(pA[i], (char*)As[s] + ldsOff[i]); pA[i] += BK2; }
#pragma unroll
            for (int i = 0; i < 2; i++) { GLDS(pB[i], (char*)Bs[s] + ldsOff[i]); pB[i] += BK2; }
        }
        WAIT_VM4();   // tile 0 resident; tile 1 still in flight
        BARRIER();

        // rotating ring-slot byte offsets: compute o0, ready o1, stage o2 (16 KB slots)
        uint32_t o0 = 0, o1 = 16384, o2 = 32768;

        const int NT = KLEN / BK2;
        for (int tk = 0; tk < NT; ++tk) {
            // issue stage for tile tk+2 into the slot freed at last barrier
            if (tk + 2 < NT) {
#pragma unroll
                for (int i = 0; i < 2; i++) { GLDS(pA[i], (char*)As[0] + o2 + ldsOff[i]); pA[i] += BK2; }
#pragma unroll
                for (int i = 0; i < 2; i++) { GLDS(pB[i], (char*)Bs[0] + o2 + ldsOff[i]); pB[i] += BK2; }
            }

            // ---- sub-step 1: a0..a3 x b0..b3 (16 MFMA) ----
            {
                short8 b0 = dsr(bAdr[0] + o0);
                short8 b1 = dsr(bAdr[1] + o0);
                short8 b2 = dsr(bAdr[2] + o0);
                short8 b3 = dsr(bAdr[3] + o0);
                short8 a0 = dsr(aAdr[0] + o0);
                short8 a1 = dsr(aAdr[1] + o0);
                short8 a2 = dsr(aAdr[2] + o0);
                short8 a3 = dsr(aAdr[3] + o0);
                WAIT_LGKM0();
                __builtin_amdgcn_sched_barrier(0);   // rule #18

                __builtin_amdgcn_s_setprio(1);
                acc[0][0] = __builtin_amdgcn_mfma_f32_16x16x32_bf16(a0, b0, acc[0][0], 0, 0, 0);
                acc[0][1] = __builtin_amdgcn_mfma_f32_16x16x32_bf16(a0, b1, acc[0][1], 0, 0, 0);
                acc[0][2] = __builtin_amdgcn_mfma_f32_16x16x32_bf16(a0, b2, acc[0][2], 0, 0, 0);
                acc[0][3] = __builtin_amdgcn_mfma_f32_16x16x32_bf16(a0, b3, acc[0][3], 0, 0, 0);
                acc[1][0] = __builtin_amdgcn_mfma_f32_16x16x32_bf16(a1, b0, acc[1][0], 0, 0, 0);
                acc[1][1] = __builtin_amdgcn_mfma_f32_16x16x32_bf16(a1, b1, acc[1][1], 0, 0, 0);
                acc[1][2] = __builtin_amdgcn_mfma_f32_16x16x32_bf16(a1, b2, acc[1][2], 0, 0, 0);
                acc[1][3] = __builtin_amdgcn_mfma_f32_16x16x32_bf16(a1, b3, acc[1][3], 0, 0, 0);
                acc[2][0] = __builtin_amdgcn_mfma_f32_16x16x32_bf16(a2, b0, acc[2][0], 0, 0, 0);
                acc[2][1] = __builtin_amdgcn_mfma_f32_16x16x32_bf16(a2, b1, acc[2][1], 0, 0, 0);
                acc[2][2] = __builtin_amdgcn_mfma_f32_16x16x32_bf16(a2, b2, acc[2][2], 0, 0, 0);
                acc[2][3] = __builtin_amdgcn_mfma_f32_16x16x32_bf16(a2, b3, acc[2][3], 0, 0, 0);
                acc[3][0] = __builtin_amdgcn_mfma_f32_16x16x32_bf16(a3, b0, acc[3][0], 0, 0, 0);
                acc[3][1] = __builtin_amdgcn_mfma_f32_16x16x32_bf16(a3, b1, acc[3][1], 0, 0, 0);
                acc[3][2] = __builtin_amdgcn_mfma_f32_16x16x32_bf16(a3, b2, acc[3][2], 0, 0, 0);
                acc[3][3] = __builtin_amdgcn_mfma_f32_16x16x32_bf16(a3, b3, acc[3][3], 0, 0, 0);
                __builtin_amdgcn_s_setprio(0);

                // ---- sub-step 2: a4..a7 x b0..b3 (16 MFMA) ----
                short8 a4 = dsr(aAdr[4] + o0);
                short8 a5 = dsr(aAdr[5] + o0);
                short8 a6 = dsr(aAdr[6] + o0);
                short8 a7 = dsr(aAdr[7] + o0);
                WAIT_LGKM0();
                __builtin_amdgcn_sched_barrier(0);   // rule #18

                __builtin_amdgcn_s_setprio(1);
                acc[4][0] = __builtin_amdgcn_mfma_f32_16x16x32_bf16(a4, b0, acc[4][0], 0, 0, 0);
                acc[4][1] = __builtin_amdgcn_mfma_f32_16x16x32_bf16(a4, b1, acc[4][1], 0, 0, 0);
                acc[4][2] = __builtin_amdgcn_mfma_f32_16x16x32_bf16(a4, b2, acc[4][2], 0, 0, 0);
                acc[4][3] = __builtin_amdgcn_mfma_f32_16x16x32_bf16(a4, b3, acc[4][3], 0, 0, 0);
                acc[5][0] = __builtin_amdgcn_mfma_f32_16x16x32_bf16(a5, b0, acc[5][0], 0, 0, 0);
                acc[5][1] = __builtin_amdgcn_mfma_f32_16x16x32_bf16(a5, b1, acc[5][1], 0, 0, 0);
                acc[5][2] = __builtin_amdgcn_mfma_f32_16x16x32_bf16(a5, b2, acc[5][2], 0, 0, 0);
                acc[5][3] = __builtin_amdgcn_mfma_f32_16x16x32_bf16(a5, b3, acc[5][3], 0, 0, 0);
                acc[6][0] = __builtin_amdgcn_mfma_f32_16x16x32_bf16(a6, b0, acc[6][0], 0, 0, 0);
                acc[6][1] = __builtin_amdgcn_mfma_f32_16x16x32_bf16(a6, b1, acc[6][1], 0, 0, 0);
                acc[6][2] = __builtin_amdgcn_mfma_f32_16x16x32_bf16(a6, b2, acc[6][2], 0, 0, 0);
                acc[6][3] = __builtin_amdgcn_mfma_f32_16x16x32_bf16(a6, b3, acc[6][3], 0, 0, 0);
                acc[7][0] = __builtin_amdgcn_mfma_f32_16x16x32_bf16(a7, b0, acc[7][0], 0, 0, 0);
                acc[7][1] = __builtin_amdgcn_mfma_f32_16x16x32_bf16(a7, b1, acc[7][1], 0, 0, 0);
                acc[7][2] = __builtin_amdgcn_mfma_f32_16x16x32_bf16(a7, b2, acc[7][2], 0, 0, 0);
                acc[7][3] = __builtin_amdgcn_mfma_f32_16x16x32_bf16(a7, b3, acc[7][3], 0, 0, 0);
                __builtin_amdgcn_s_setprio(0);
            }

            // counted drain: tile tk+1 must be resident; tk+2's 4 loads stay in flight
            if (tk + 1 < NT) {
                if (tk + 2 < NT) WAIT_VM4();
                else             WAIT_VM0();
                BARRIER();
            }
            uint32_t tmp = o0; o0 = o1; o1 = o2; o2 = tmp;
        }

        // ---- epilogue: row = m0+wm*128+mi*16+g*4+q; col = n0+wn*64+nj*16+r16 ----
#pragma unroll
        for (int mi = 0; mi < 8; ++mi) {
#pragma unroll
            for (int nj = 0; nj < 4; ++nj) {
#pragma unroll
                for (int qq = 0; qq < 4; ++qq) {
                    int lr = wm * 128 + mi * 16 + g * 4 + qq;
                    if (m0 + lr < n_e) {
                        int col = n0 + wn * 64 + nj * 16 + r16;
                        float v = acc[mi][nj][qq];
                        if (SILU) {
                            v = v / (1.f + __expf(-v));
                            Hout[(size_t)(base + m0 + lr) * NW + col] = f2bf(v);
                        } else {
                            int tok = list[e * TOKENS + m0 + lr];
                            atomicAdd(&Yout[(size_t)tok * NW + col], v);
                        }
                    }
                }
            }
        }
    }
}

extern "C" void kernel_launch(void* const* d_in, const int* in_sizes, int n_in,
                              void* d_out, int out_size, void* d_ws, size_t ws_size,
                              hipStream_t stream) {
    const float* X  = (const float*)d_in[0];
    const float* Wr = (const float*)d_in[1];
    const float* W1 = (const float*)d_in[2];
    const float* W2 = (const float*)d_in[3];
    float* Y = (float*)d_out;

    char* ws = (char*)d_ws;
    int* cnt  = (int*)(ws + 0);
    int* off  = (int*)(ws + 64);
    int* wbA  = (int*)(ws + 128);
    int* wbB  = (int*)(ws + 192);
    int* qctr = (int*)(ws + 256);
    int* list = (int*)(ws + 1024);                               // 128 KB
    unsigned short* Xb = (unsigned short*)(ws + (1ull << 20));   // 8 MB
    unsigned short* WT = (unsigned short*)(ws + (16ull << 20));  // 64 MB (W1T, then W2T)
    unsigned short* H  = (unsigned short*)(ws + (80ull << 20));  // 64 MB

    hipMemsetAsync(d_out, 0, (size_t)out_size * sizeof(float), stream);
    hipMemsetAsync(cnt, 0, 32, stream);

    cvt_x<<<TOKENS * DDIM / (256 * 8), 256, 0, stream>>>(X, Xb, TOKENS * DDIM);
    router<<<TOKENS / 4, 256, 0, stream>>>(X, Wr, cnt, list);
    setup<<<1, 64, 0, stream>>>(cnt, off, wbA, wbB, qctr);

    // W1 [E][D][F] -> W1T [E][F][D] bf16
    transpose_cvt<<<dim3(FDIM / 32, DDIM / 32, NEXP), 256, 0, stream>>>(W1, WT, DDIM, FDIM);
    // Pass A: H[slot][F] = silu(X[tok] @ W1[e]); K=1024, 16 n-tiles of 256
    gemm_moe15<true, true, 1><<<256, 512, 0, stream>>>(
        Xb, WT, cnt, off, list, wbA, qctr + 0, H, nullptr, DDIM, DDIM, FDIM);

    // W2 [E][F][D] -> W2T [E][D][F] bf16 (reuses WT)
    transpose_cvt<<<dim3(DDIM / 32, FDIM / 32, NEXP), 256, 0, stream>>>(W2, WT, FDIM, DDIM);
    // Pass B: Y[tok][D] += H[slot] @ W2[e]; 4 n-tiles x 4 k-chunks of 1024
    gemm_moe15<false, false, 4><<<256, 512, 0, stream>>>(
        H, WT, cnt, off, list, wbB, qctr + 1, nullptr, Y, FDIM, FDIM / 4, DDIM);
}

// Round 16
// 480.107 us; speedup vs baseline: 1.2120x; 1.1749x over previous
//
#include <hip/hip_runtime.h>
#include <hip/hip_bf16.h>
#include <stdint.h>

#define TOKENS 4096
#define DDIM 1024
#define FDIM 4096
#define NEXP 8
#define BM 128
#define BN 128
#define BK2 32

typedef __attribute__((ext_vector_type(4))) float f32x4;
typedef __attribute__((ext_vector_type(8))) short short8;

__device__ __forceinline__ unsigned short f2bf(float f) {
    union { float f; uint32_t u; } v; v.f = f;
    uint32_t u = v.u;
    return (unsigned short)((u + 0x7fff + ((u >> 16) & 1)) >> 16);
}

#define BARRIER() asm volatile("s_barrier" ::: "memory")
#define WAIT_VM0() asm volatile("s_waitcnt vmcnt(0)" ::: "memory")
#define WAIT_VM4() asm volatile("s_waitcnt vmcnt(4)" ::: "memory")
#define WAIT_VM8() asm volatile("s_waitcnt vmcnt(8)" ::: "memory")
#define WAIT_LGKM0() asm volatile("s_waitcnt lgkmcnt(0)" ::: "memory")
#define GLDS(SRC, DST) __builtin_amdgcn_global_load_lds( \
    (const __attribute__((address_space(1))) void*)(SRC), \
    (__attribute__((address_space(3))) void*)(DST), 16, 0, 0)

// opaque asm LDS read: explicit waits control all ordering (rule #18 applied at use)
__device__ __forceinline__ short8 dsr(uint32_t addr) {
    short8 d;
    asm volatile("ds_read_b128 %0, %1" : "=v"(d) : "v"(addr));
    return d;
}

// ------------- transpose + cvt: in [E][R][C] f32 -> out [E][C][R] bf16 -------------
__global__ __launch_bounds__(256) void transpose_cvt(const float* __restrict__ in,
                                                     unsigned short* __restrict__ out,
                                                     int R, int C) {
    __shared__ float tile[32][33];
    int e = blockIdx.z;
    int r0 = blockIdx.y * 32, c0 = blockIdx.x * 32;
    const float* src = in + (size_t)e * R * C;
    unsigned short* dst = out + (size_t)e * R * C;
    int t = threadIdx.x;
    int rr = t >> 3;
    int cc = (t & 7) * 4;
    float4 v = *(const float4*)(src + (size_t)(r0 + rr) * C + c0 + cc);
    tile[rr][cc + 0] = v.x; tile[rr][cc + 1] = v.y;
    tile[rr][cc + 2] = v.z; tile[rr][cc + 3] = v.w;
    __syncthreads();
    int oc = rr;
    int orr = cc;
    ushort4 o;
    o.x = f2bf(tile[orr + 0][oc]);
    o.y = f2bf(tile[orr + 1][oc]);
    o.z = f2bf(tile[orr + 2][oc]);
    o.w = f2bf(tile[orr + 3][oc]);
    *(ushort4*)(dst + (size_t)(c0 + oc) * R + r0 + orr) = o;
}

// ---- fused router: top-2 of 8 logits + X f32->bf16 cvt (vectorized) ----
__global__ __launch_bounds__(256) void router_cvt(const float* __restrict__ x,
                                                  const float* __restrict__ wr,
                                                  unsigned short* __restrict__ xb,
                                                  int* __restrict__ cnt,
                                                  int* __restrict__ list) {
    __shared__ float wl[NEXP * DDIM];   // 32 KB
    int t = threadIdx.x;
    for (int i = t * 4; i < NEXP * DDIM; i += 256 * 4)
        *(float4*)&wl[i] = *(const float4*)&wr[i];
    __syncthreads();
    int tok = blockIdx.x * 4 + (t >> 6);
    int lane = t & 63;
    float acc[NEXP];
#pragma unroll
    for (int e = 0; e < NEXP; e++) acc[e] = 0.f;
    const float* xr = x + (size_t)tok * DDIM;
    unsigned short* xbr = xb + (size_t)tok * DDIM;
#pragma unroll
    for (int c = 0; c < 4; c++) {
        int d = c * 256 + lane * 4;
        float4 v = *(const float4*)(xr + d);
        ushort4 o;
        o.x = f2bf(v.x); o.y = f2bf(v.y); o.z = f2bf(v.z); o.w = f2bf(v.w);
        *(ushort4*)(xbr + d) = o;
#pragma unroll
        for (int e = 0; e < NEXP; e++) {
            float4 w4 = *(const float4*)&wl[e * DDIM + d];
            acc[e] += v.x * w4.x + v.y * w4.y + v.z * w4.z + v.w * w4.w;
        }
    }
#pragma unroll
    for (int e = 0; e < NEXP; e++) {
#pragma unroll
        for (int off = 32; off; off >>= 1) acc[e] += __shfl_xor(acc[e], off);
    }
    if (lane == 0) {
        int e1 = 0; float v1 = acc[0];
        for (int e = 1; e < NEXP; e++) if (acc[e] > v1) { v1 = acc[e]; e1 = e; }
        int e2 = -1; float v2 = -1e30f;
        for (int e = 0; e < NEXP; e++) if (e != e1 && acc[e] > v2) { v2 = acc[e]; e2 = e; }
        int p1 = atomicAdd(&cnt[e1], 1);
        list[e1 * TOKENS + p1] = tok;
        int p2 = atomicAdd(&cnt[e2], 1);
        list[e2 * TOKENS + p2] = tok;
    }
}

// ---------------- setup: offsets, work bases, queue reset ----------------
__global__ void setup(const int* __restrict__ cnt, int* __restrict__ off,
                      int* __restrict__ wbA, int* __restrict__ wbB,
                      int* __restrict__ qctr) {
    if (threadIdx.x == 0) {
        int s = 0, ta = 0, tb = 0;
        for (int e = 0; e < NEXP; e++) {
            off[e] = s; s += cnt[e];
            wbA[e] = ta; wbB[e] = tb;
            int ntm = (cnt[e] + BM - 1) / BM;
            ta += ntm * (FDIM / BN);        // pass A: 32 n-tiles
            tb += ntm * (DDIM / BN) * 2;    // pass B: 8 n-tiles x 2 k-chunks
        }
        wbA[NEXP] = ta; wbB[NEXP] = tb;
        qctr[0] = 0; qctr[1] = 0;
    }
}

// ---------------- persistent grouped GEMM: R8 verbatim + fused transpose tail ----------------
// 128^2, BK=32, 3-slot ring, prefetch distance 2, counted vmcnt(4), 3 blk/CU.
// Queue items >= total are W2-transpose slabs (32 f-rows x full D), absorbed in the tail.
template <bool GATHER_A, bool SILU, int KSPLIT>
__global__ __launch_bounds__(256, 3) void gemm_moe16(
    const unsigned short* __restrict__ Abase,
    const unsigned short* __restrict__ Wt,      // [E][NW][KD] bf16
    const int* __restrict__ cnt, const int* __restrict__ off,
    const int* __restrict__ list,
    const int* __restrict__ wbase,
    int* __restrict__ qctr,
    unsigned short* __restrict__ Hout,          // SILU out, stride NW
    float* __restrict__ Yout,                   // atomic out, stride NW
    const float* __restrict__ TRsrc,            // fused transpose: src [E][FDIM][DDIM] f32
    unsigned short* __restrict__ TRdst,         // fused transpose: dst [E][DDIM][FDIM] bf16
    int extra,                                  // number of trailing transpose items
    int KD, int KLEN, int NW) {
    __shared__ alignas(16) unsigned short As[3][BM * BK2];  // 3 x 8 KB
    __shared__ alignas(16) unsigned short Bs[3][BN * BK2];  // 3 x 8 KB
    __shared__ int wsh;

    const int t = threadIdx.x;
    const int lane = t & 63;
    const int wid = t >> 6;
    const int wm = wid >> 1, wn = wid & 1;
    const int r16 = lane & 15, g = lane >> 4;
    const int total = wbase[NEXP];
    const int totalAll = total + extra;

    // frag addresses within a slot (slot 0 base); chunk g stored at g^((row>>1)&3)
    const uint32_t asB = (uint32_t)(uintptr_t)&As[0][0];
    const uint32_t bsB = (uint32_t)(uintptr_t)&Bs[0][0];
    uint32_t aAdr[4], bAdr[4];
#pragma unroll
    for (int mi = 0; mi < 4; mi++) {
        int row = wm * 64 + mi * 16 + r16;
        aAdr[mi] = asB + row * 64 + ((g ^ ((row >> 1) & 3)) << 4);
    }
#pragma unroll
    for (int nj = 0; nj < 4; nj++) {
        int row = wn * 64 + nj * 16 + r16;
        bAdr[nj] = bsB + row * 64 + ((g ^ ((row >> 1) & 3)) << 4);
    }

    for (;;) {
        if (t == 0) wsh = atomicAdd(qctr, 1);
        __syncthreads();
        int w = wsh;
        if (w >= totalAll) break;

        if (w >= total) {
            // ---- fused W2-transpose slab: 32 f-rows x full DDIM, tile-by-tile via LDS ----
            int tr = w - total;
            int e = tr >> 7;                  // FDIM/32 = 128 slabs per expert
            int f0 = (tr & 127) << 5;
            const float* src = TRsrc + (size_t)e * FDIM * DDIM;
            unsigned short* dst = TRdst + (size_t)e * FDIM * DDIM;
            float* tile = (float*)&As[0][0];  // 32x33 f32 = 4.2 KB, aliases gemm LDS
            int rr = t >> 3;
            int cc = (t & 7) * 4;
            for (int c0 = 0; c0 < DDIM; c0 += 32) {
                float4 v = *(const float4*)(src + (size_t)(f0 + rr) * DDIM + c0 + cc);
                tile[rr * 33 + cc + 0] = v.x; tile[rr * 33 + cc + 1] = v.y;
                tile[rr * 33 + cc + 2] = v.z; tile[rr * 33 + cc + 3] = v.w;
                __syncthreads();
                ushort4 o;
                o.x = f2bf(tile[(cc + 0) * 33 + rr]);
                o.y = f2bf(tile[(cc + 1) * 33 + rr]);
                o.z = f2bf(tile[(cc + 2) * 33 + rr]);
                o.w = f2bf(tile[(cc + 3) * 33 + rr]);
                *(ushort4*)(dst + (size_t)(c0 + rr) * FDIM + f0 + cc) = o;
                __syncthreads();
            }
            continue;
        }

        // ---- decode: expert e; (n-tile [, k-chunk]) outer, m-tile inner ----
        int e = 0;
        while (e < NEXP - 1 && w >= wbase[e + 1]) e++;
        w -= wbase[e];
        const int n_e = cnt[e];
        const int ntm = (n_e + BM - 1) >> 7;
        int idx = w / ntm;
        const int mtile = w - idx * ntm;
        int kc = 0;
        if (KSPLIT == 2) { kc = idx & 1; idx >>= 1; }
        const int m0 = mtile * BM;
        const int n0 = idx * BN;
        const int base = off[e];
        const int k0 = kc * KLEN;

        // ---- staging pointers: 2 A + 2 B chunks of 16 B per thread per tile ----
        const unsigned short* pA[2];
        const unsigned short* pB[2];
        int ldsOff[2];
#pragma unroll
        for (int i = 0; i < 2; i++) {
            int c = i * 256 + t;
            int row = c >> 2, p = c & 3;
            int cg = p ^ ((row >> 1) & 3);
            int arow = m0 + row; if (arow >= n_e) arow = n_e - 1;
            size_t grow = GATHER_A ? (size_t)list[e * TOKENS + arow] : (size_t)(base + arow);
            pA[i] = Abase + grow * (size_t)KD + k0 + (cg << 3);
            pB[i] = Wt + ((size_t)e * NW + n0 + row) * (size_t)KD + k0 + (cg << 3);
            ldsOff[i] = c * 16;
        }

        f32x4 acc[4][4];
#pragma unroll
        for (int i = 0; i < 4; i++)
#pragma unroll
            for (int j = 0; j < 4; j++) acc[i][j] = f32x4{0.f, 0.f, 0.f, 0.f};

        // ---- prologue: stage tiles 0,1 into slots 0,1 ----
#pragma unroll
        for (int s = 0; s < 2; ++s) {
#pragma unroll
            for (int i = 0; i < 2; i++) { GLDS(pA[i], (char*)As[s] + ldsOff[i]); pA[i] += BK2; }
#pragma unroll
            for (int i = 0; i < 2; i++) { GLDS(pB[i], (char*)Bs[s] + ldsOff[i]); pB[i] += BK2; }
        }
        WAIT_VM4();   // tile 0 resident; tile 1 still in flight
        BARRIER();

        // rotating ring-slot byte offsets: compute o0, ready o1, stage o2
        uint32_t o0 = 0, o1 = 8192, o2 = 16384;

        const int NT = KLEN / BK2;
        for (int tk = 0; tk < NT; ++tk) {
            // issue stage for tile tk+2 into the slot freed at last barrier
            if (tk + 2 < NT) {
#pragma unroll
                for (int i = 0; i < 2; i++) { GLDS(pA[i], (char*)As[0] + o2 + ldsOff[i]); pA[i] += BK2; }
#pragma unroll
                for (int i = 0; i < 2; i++) { GLDS(pB[i], (char*)Bs[0] + o2 + ldsOff[i]); pB[i] += BK2; }
            }

            // fragment loads: opaque asm ds_read_b128 from compute slot
            short8 a0 = dsr(aAdr[0] + o0);
            short8 a1 = dsr(aAdr[1] + o0);
            short8 a2 = dsr(aAdr[2] + o0);
            short8 a3 = dsr(aAdr[3] + o0);
            short8 b0 = dsr(bAdr[0] + o0);
            short8 b1 = dsr(bAdr[1] + o0);
            short8 b2 = dsr(bAdr[2] + o0);
            short8 b3 = dsr(bAdr[3] + o0);
            WAIT_LGKM0();
            __builtin_amdgcn_sched_barrier(0);   // rule #18

            __builtin_amdgcn_s_setprio(1);
            acc[0][0] = __builtin_amdgcn_mfma_f32_16x16x32_bf16(a0, b0, acc[0][0], 0, 0, 0);
            acc[0][1] = __builtin_amdgcn_mfma_f32_16x16x32_bf16(a0, b1, acc[0][1], 0, 0, 0);
            acc[0][2] = __builtin_amdgcn_mfma_f32_16x16x32_bf16(a0, b2, acc[0][2], 0, 0, 0);
            acc[0][3] = __builtin_amdgcn_mfma_f32_16x16x32_bf16(a0, b3, acc[0][3], 0, 0, 0);
            acc[1][0] = __builtin_amdgcn_mfma_f32_16x16x32_bf16(a1, b0, acc[1][0], 0, 0, 0);
            acc[1][1] = __builtin_amdgcn_mfma_f32_16x16x32_bf16(a1, b1, acc[1][1], 0, 0, 0);
            acc[1][2] = __builtin_amdgcn_mfma_f32_16x16x32_bf16(a1, b2, acc[1][2], 0, 0, 0);
            acc[1][3] = __builtin_amdgcn_mfma_f32_16x16x32_bf16(a1, b3, acc[1][3], 0, 0, 0);
            acc[2][0] = __builtin_amdgcn_mfma_f32_16x16x32_bf16(a2, b0, acc[2][0], 0, 0, 0);
            acc[2][1] = __builtin_amdgcn_mfma_f32_16x16x32_bf16(a2, b1, acc[2][1], 0, 0, 0);
            acc[2][2] = __builtin_amdgcn_mfma_f32_16x16x32_bf16(a2, b2, acc[2][2], 0, 0, 0);
            acc[2][3] = __builtin_amdgcn_mfma_f32_16x16x32_bf16(a2, b3, acc[2][3], 0, 0, 0);
            acc[3][0] = __builtin_amdgcn_mfma_f32_16x16x32_bf16(a3, b0, acc[3][0], 0, 0, 0);
            acc[3][1] = __builtin_amdgcn_mfma_f32_16x16x32_bf16(a3, b1, acc[3][1], 0, 0, 0);
            acc[3][2] = __builtin_amdgcn_mfma_f32_16x16x32_bf16(a3, b2, acc[3][2], 0, 0, 0);
            acc[3][3] = __builtin_amdgcn_mfma_f32_16x16x32_bf16(a3, b3, acc[3][3], 0, 0, 0);
            __builtin_amdgcn_s_setprio(0);

            // counted drain: tile tk+1 must be resident; tk+2's 4 loads stay in flight
            if (tk + 1 < NT) {
                if (tk + 2 < NT) WAIT_VM4();
                else             WAIT_VM0();
                BARRIER();
            }
            uint32_t tmp = o0; o0 = o1; o1 = o2; o2 = tmp;
        }

        // ---- epilogue: row = m0+wm*64+mi*16+g*4+q; col = n0+wn*64+nj*16+r16 ----
#pragma unroll
        for (int mi = 0; mi < 4; ++mi) {
#pragma unroll
            for (int nj = 0; nj < 4; ++nj) {
#pragma unroll
                for (int qq = 0; qq < 4; ++qq) {
                    int lr = wm * 64 + mi * 16 + g * 4 + qq;
                    if (m0 + lr < n_e) {
                        int col = n0 + wn * 64 + nj * 16 + r16;
                        float v = acc[mi][nj][qq];
                        if (SILU) {
                            v = v / (1.f + __expf(-v));
                            Hout[(size_t)(base + m0 + lr) * NW + col] = f2bf(v);
                        } else {
                            int tok = list[e * TOKENS + m0 + lr];
                            atomicAdd(&Yout[(size_t)tok * NW + col], v);
                        }
                    }
                }
            }
        }
    }
}

extern "C" void kernel_launch(void* const* d_in, const int* in_sizes, int n_in,
                              void* d_out, int out_size, void* d_ws, size_t ws_size,
                              hipStream_t stream) {
    const float* X  = (const float*)d_in[0];
    const float* Wr = (const float*)d_in[1];
    const float* W1 = (const float*)d_in[2];
    const float* W2 = (const float*)d_in[3];
    float* Y = (float*)d_out;

    char* ws = (char*)d_ws;
    int* cnt  = (int*)(ws + 0);
    int* off  = (int*)(ws + 64);
    int* wbA  = (int*)(ws + 128);
    int* wbB  = (int*)(ws + 192);
    int* qctr = (int*)(ws + 256);
    int* list = (int*)(ws + 1024);                               // 128 KB
    unsigned short* Xb  = (unsigned short*)(ws + (1ull << 20));   // 8 MB
    unsigned short* WT1 = (unsigned short*)(ws + (16ull << 20));  // 64 MB
    unsigned short* H   = (unsigned short*)(ws + (80ull << 20));  // 64 MB

    // Fused-transpose mode needs a second 64 MB weight buffer at 144 MB.
    const bool fuse = ws_size >= (208ull << 20);
    unsigned short* WT2 = fuse ? (unsigned short*)(ws + (144ull << 20)) : WT1;
    const int extraA = fuse ? NEXP * (FDIM / 32) : 0;   // 1024 slab items

    hipMemsetAsync(d_out, 0, (size_t)out_size * sizeof(float), stream);
    hipMemsetAsync(cnt, 0, 32, stream);

    router_cvt<<<TOKENS / 4, 256, 0, stream>>>(X, Wr, Xb, cnt, list);
    setup<<<1, 64, 0, stream>>>(cnt, off, wbA, wbB, qctr);

    // W1 [E][D][F] -> W1T [E][F][D] bf16 (must precede pass A)
    transpose_cvt<<<dim3(FDIM / 32, DDIM / 32, NEXP), 256, 0, stream>>>(W1, WT1, DDIM, FDIM);

    // Pass A: H[slot][F] = silu(X[tok] @ W1[e]); K=1024.
    // Trailing queue items transpose W2 [E][F][D] f32 -> WT2 [E][D][F] bf16 in the tail.
    gemm_moe16<true, true, 1><<<768, 256, 0, stream>>>(
        Xb, WT1, cnt, off, list, wbA, qctr + 0, H, nullptr,
        W2, WT2, extraA, DDIM, DDIM, FDIM);

    if (!fuse) {
        // fallback: separate W2 transpose (reuses WT1; pass A has finished with it)
        transpose_cvt<<<dim3(DDIM / 32, FDIM / 32, NEXP), 256, 0, stream>>>(W2, WT2, FDIM, DDIM);
    }

    // Pass B: Y[tok][D] += H[slot] @ W2[e]; K split 2 x 2048
    gemm_moe16<false, false, 2><<<768, 256, 0, stream>>>(
        H, WT2, cnt, off, list, wbB, qctr + 1, nullptr, Y,
        nullptr, nullptr, 0, FDIM, FDIM / 2, DDIM);
}